// Round 7
// baseline (153.547 us; speedup 1.0000x reference)
//
#include <hip/hip_runtime.h>
#include <hip/hip_bf16.h>

#define CC 256
#define NN 4096
#define CQ 32
#define LOG2E 1.4426950408889634f

using short4v = __attribute__((ext_vector_type(4))) short;
using short8 = __attribute__((ext_vector_type(8))) short;
using f32x4  = __attribute__((ext_vector_type(4))) float;

static __device__ __forceinline__ short f2bf(float f) {
  __hip_bfloat16 h = __float2bfloat16(f);
  return *reinterpret_cast<short*>(&h);
}

// ---------------------------------------------------------------------------
// Kernel 0 (FUSED): blocks 0..39 = prep (build frag-linear Wf, unchanged
// math); blocks 40..1063 = x transpose: xT[b][n][c] = bf16(x[b][c][n]).
// Transpose tile 64n x 64c per block: reads are 256 B contiguous runs of x
// rows (vs qkv's old 16 KB-strided scalar gather), LDS stride 70 shorts
// (lane*35 dwords, 35 coprime 32 -> 2-way = free), writes 2x16 B contiguous
// per thread.  This moves the [C][N]->[N][C] transpose out of qkv entirely.
// ---------------------------------------------------------------------------
__global__ __launch_bounds__(256) void xpose_prep_kernel(
    const float* __restrict__ x,
    const float* __restrict__ Wq, const float* __restrict__ Wk,
    const float* __restrict__ Wv, __hip_bfloat16* __restrict__ Wf,
    __hip_bfloat16* __restrict__ xT)
{
  if (blockIdx.x < 40) {
    // ---- prep: identical to previous prep_kernel ----
    int t = blockIdx.x*256 + threadIdx.x;          // 0..10239
    int lane = t & 63, frag = t >> 6;              // frag = tile*8 + kc
    int tile = frag >> 3, kc = frag & 7;
    int l15 = lane & 15, quad = lane >> 4;
    int R = tile*16 + l15;                         // output row 0..319
    int k0 = kc*32 + quad*8;
    const float* src;
    if (R < 32)       src = Wq + (size_t)R*CC + k0;
    else if (R < 64)  src = Wk + (size_t)(R-32)*CC + k0;
    else              src = Wv + (size_t)(R-64)*CC + k0;
    float4 a = *(const float4*)(src);
    float4 c = *(const float4*)(src + 4);
    short8 o;
    o[0]=f2bf(a.x); o[1]=f2bf(a.y); o[2]=f2bf(a.z); o[3]=f2bf(a.w);
    o[4]=f2bf(c.x); o[5]=f2bf(c.y); o[6]=f2bf(c.z); o[7]=f2bf(c.w);
    *reinterpret_cast<short8*>(reinterpret_cast<short*>(Wf) + (size_t)t*8) = o;
    return;
  }

  // ---- transpose: tile (b, n0, c0) ----
  const int bt = blockIdx.x - 40;                  // 0..1023
  const int b  = bt >> 8;                          // 4 batches
  const int t2 = bt & 255;                         // 256 tiles/batch
  const int c0 = (t2 & 3) * 64;                    // 4 c-tiles
  const int n0 = (t2 >> 2) * 64;                   // 64 n-tiles

  __shared__ short T[64][70];                      // [n-lane][c-off], 8960 B
  const int tid = threadIdx.x;
  const int lane = tid & 63;
  const int w = tid >> 6;                          // wave 0..3

  const float* xb = x + (size_t)b*CC*NN;
#pragma unroll
  for (int i = 0; i < 16; i++) {
    int c = c0 + w*16 + i;
    float v = xb[(size_t)c*NN + n0 + lane];        // 256 B coalesced / instr
    T[lane][w*16 + i] = f2bf(v);                   // 2-way banks (free)
  }
  __syncthreads();

  // write phase: thread covers row nr = tid>>2, c-chunk seg = tid&3 (16 c)
  const int nr = tid >> 2, seg = tid & 3;
  const int* rp = reinterpret_cast<const int*>(&T[nr][seg*16]);  // 4B-aligned
  short vbuf[16];
#pragma unroll
  for (int j = 0; j < 8; j++)
    *reinterpret_cast<int*>(&vbuf[2*j]) = rp[j];
  short* dst = reinterpret_cast<short*>(xT) + ((size_t)b*NN + n0 + nr)*CC + c0 + seg*16;
  *(short8*)(dst)     = *reinterpret_cast<short8*>(&vbuf[0]);
  *(short8*)(dst + 8) = *reinterpret_cast<short8*>(&vbuf[8]);
}

// ---------------------------------------------------------------------------
// Kernel 1: QKV via MFMA.  Same structure as R6 (grid 128x4, 256 threads,
// frag-linear LDS Xl, zero-conflict staging writes + B reads, packed q/k
// stores, v repack), but staging now reads xT[n][c] with 16 B CONTIGUOUS
// short8 loads (4 per thread) — the 32 strided scalar fp32 loads + 32 cvts
// per thread are gone (moved to the coalesced transpose pass).
// Numerics bit-identical (same bf16 values, same accumulation order).
// ---------------------------------------------------------------------------
__global__ __launch_bounds__(256) void qkv_kernel(
    const __hip_bfloat16* __restrict__ xT, const __hip_bfloat16* __restrict__ Wf,
    const float* __restrict__ bq, const float* __restrict__ bk,
    const float* __restrict__ bv,
    __hip_bfloat16* __restrict__ qb, __hip_bfloat16* __restrict__ kb,
    __hip_bfloat16* __restrict__ vb)
{
  const int b  = blockIdx.y;
  const int n0 = blockIdx.x * 32;
  const int tid = threadIdx.x;
  const int lane = tid & 63;
  const int w = __builtin_amdgcn_readfirstlane(tid >> 6);  // wave 0..3
  const int l15 = lane & 15, quad = lane >> 4;

  __shared__ __align__(16) short Xl[16*64*8];     // frag-linear x, 16384 B
  __shared__ __align__(16) short Vr[4][16][32];   // per-wave repack, 4096 B

  // ---- stage x tile from xT: pure contiguous copy, 1024 slots x 16 B ----
  const short* xTs = reinterpret_cast<const short*>(xT) + (size_t)b*NN*CC;
#pragma unroll
  for (int i = 0; i < 4; i++) {
    int s = tid + 256*i;                 // slot 0..1023
    int g = s >> 6, ln = s & 63;         // group (nr*8+kc), lane-slot
    int nr = g >> 3, kc = g & 7;
    int l15s = ln & 15, quads = ln >> 4;
    const short* src = xTs + (size_t)(n0 + nr*16 + l15s)*CC + kc*32 + quads*8;
    *reinterpret_cast<short8*>(&Xl[(size_t)s*8]) = *(const short8*)src;
  }
  __syncthreads();

  const short* wfp = reinterpret_cast<const short*>(Wf);
  short* qb_s = reinterpret_cast<short*>(qb) + (size_t)b*NN*CQ;
  short* kb_s = reinterpret_cast<short*>(kb) + (size_t)b*NN*CQ;
  short* vb_s = reinterpret_cast<short*>(vb) + (size_t)b*CC*NN;

#define QKV_TILE(T) { \
    const int t_ = (T); \
    short8 Af[8]; \
    _Pragma("unroll") \
    for (int kc = 0; kc < 8; kc++) \
      Af[kc] = *(const short8*)(wfp + ((size_t)(t_*8 + kc)*64 + lane)*8); \
    f32x4 ac0 = {0.f,0.f,0.f,0.f}, ac1 = {0.f,0.f,0.f,0.f}; \
    _Pragma("unroll") \
    for (int kc = 0; kc < 8; kc++) { \
      short8 B0 = *(const short8*)(&Xl[((     kc)*64 + lane)*8]); \
      short8 B1 = *(const short8*)(&Xl[((8 +  kc)*64 + lane)*8]); \
      ac0 = __builtin_amdgcn_mfma_f32_16x16x32_bf16(Af[kc], B0, ac0, 0,0,0); \
      ac1 = __builtin_amdgcn_mfma_f32_16x16x32_bf16(Af[kc], B1, ac1, 0,0,0); \
    } \
    if (t_ < 2) { \
      int d0 = t_*16 + quad*4; \
      short4v p0, p1; \
      _Pragma("unroll") \
      for (int r = 0; r < 4; r++) { \
        float bb = bq[d0 + r]; \
        p0[r] = f2bf(LOG2E*(ac0[r] + bb)); \
        p1[r] = f2bf(LOG2E*(ac1[r] + bb)); \
      } \
      *(short4v*)(qb_s + (size_t)(n0      + l15)*CQ + d0) = p0; \
      *(short4v*)(qb_s + (size_t)(n0 + 16 + l15)*CQ + d0) = p1; \
    } else if (t_ < 4) { \
      int d0 = (t_-2)*16 + quad*4; \
      short4v p0, p1; \
      _Pragma("unroll") \
      for (int r = 0; r < 4; r++) { \
        float bb = bk[d0 + r]; \
        p0[r] = f2bf(ac0[r] + bb); \
        p1[r] = f2bf(ac1[r] + bb); \
      } \
      *(short4v*)(kb_s + (size_t)(n0      + l15)*CQ + d0) = p0; \
      *(short4v*)(kb_s + (size_t)(n0 + 16 + l15)*CQ + d0) = p1; \
    } else { \
      int rv0 = (t_-4)*16; \
      _Pragma("unroll") \
      for (int r = 0; r < 4; r++) { \
        float bb = bv[rv0 + quad*4 + r]; \
        Vr[w][quad*4 + r][     l15] = f2bf(ac0[r] + bb); \
        Vr[w][quad*4 + r][16 + l15] = f2bf(ac1[r] + bb); \
      } \
      int row = lane >> 2, cb = (lane & 3)*8; \
      short8 tv = *(const short8*)(&Vr[w][row][cb]); \
      *(short8*)(vb_s + (size_t)(rv0 + row)*NN + n0 + cb) = tv; \
    } }

  QKV_TILE(w);
  QKV_TILE(4 + w);
  QKV_TILE(8 + w);
  QKV_TILE(12 + w);
  QKV_TILE(16 + w);
#undef QKV_TILE
}

// ---------------------------------------------------------------------------
// Kernel 2: O = softmax(QK^T) V, epilogue gamma*O + x.  EXACT v1 kernel
// (proven 70.4 us).  UNCHANGED.
// ---------------------------------------------------------------------------
__global__ __launch_bounds__(512, 2) void attn_kernel(
    const __hip_bfloat16* __restrict__ qb, const __hip_bfloat16* __restrict__ kb,
    const __hip_bfloat16* __restrict__ vb,
    const float* __restrict__ x, const float* __restrict__ gamma,
    float* __restrict__ out)
{
  const int Bk = blockIdx.x;
  const int b = (Bk & 7) >> 1;                       // 2 XCDs per batch
  const int n0 = ((Bk >> 3)*2 + (Bk & 1)) * 64;      // n-tile 0..63
  const int tid = threadIdx.x;
  const int lane = tid & 63;
  const int w = __builtin_amdgcn_readfirstlane(tid >> 6);   // 0..7
  const int sg = w & 3;                               // S row-group / c-strip
  const int mh = w >> 2;                              // m-half 0/1
  const int l15 = lane & 15, quad = lane >> 4;

  __shared__ __align__(16) short Vs[256][72];   // [c][m 0..64], 36864 B
  __shared__ __align__(16) short Ps[64][72];    // [n][m 0..64], 9216 B
  __shared__ float Lbuf2[2][64];

  const short* qbase = (const short*)qb + (size_t)b*NN*CQ;
  const short* kbase = (const short*)kb + (size_t)b*NN*CQ;
  const short* vbase = (const short*)vb + (size_t)b*CC*NN;

  short8 aq = *(const short8*)(qbase + (size_t)(n0 + sg*16 + l15)*CQ + quad*8);

  // V staging: thread covers row vr, m-half sh (32 shorts = 4 chunks)
  const int vr = tid >> 1, sh = tid & 1;

  short8 vf0, vf1, vf2, vf3, kf0, kf1;
  // preload tile 0
#pragma unroll
  for (int j = 0; j < 4; j++) {
    short8 t = *(const short8*)(vbase + (size_t)vr*NN + sh*32 + j*8);
    if (j == 0) vf0 = t; else if (j == 1) vf1 = t; else if (j == 2) vf2 = t; else vf3 = t;
  }
  kf0 = *(const short8*)(kbase + (size_t)(mh*32 +      l15)*CQ + quad*8);
  kf1 = *(const short8*)(kbase + (size_t)(mh*32 + 16 + l15)*CQ + quad*8);
  *(short8*)(&Vs[vr][sh*32 +  0]) = vf0;
  *(short8*)(&Vs[vr][sh*32 +  8]) = vf1;
  *(short8*)(&Vs[vr][sh*32 + 16]) = vf2;
  *(short8*)(&Vs[vr][sh*32 + 24]) = vf3;

  f32x4 acc[4][4];
#pragma unroll
  for (int cg = 0; cg < 4; cg++)
#pragma unroll
    for (int ng = 0; ng < 4; ng++) acc[cg][ng] = (f32x4){0.f,0.f,0.f,0.f};
  float lsum[4] = {0.f,0.f,0.f,0.f};

  __syncthreads();

  for (int T = 0; T < 64; T++) {
    // prefetch tile T+1 into regs
    short8 nv0, nv1, nv2, nv3, nk0, nk1;
    if (T < 63) {
      const short* vp = vbase + (size_t)vr*NN + (T+1)*64 + sh*32;
      nv0 = *(const short8*)(vp);
      nv1 = *(const short8*)(vp + 8);
      nv2 = *(const short8*)(vp + 16);
      nv3 = *(const short8*)(vp + 24);
      nk0 = *(const short8*)(kbase + (size_t)((T+1)*64 + mh*32 +      l15)*CQ + quad*8);
      nk1 = *(const short8*)(kbase + (size_t)((T+1)*64 + mh*32 + 16 + l15)*CQ + quad*8);
    }

    // S' for rows sg*16.., m-half mh
    f32x4 z = {0.f,0.f,0.f,0.f};
    f32x4 S0 = __builtin_amdgcn_mfma_f32_16x16x32_bf16(aq, kf0, z, 0,0,0);
    f32x4 S1 = __builtin_amdgcn_mfma_f32_16x16x32_bf16(aq, kf1, z, 0,0,0);
#pragma unroll
    for (int r = 0; r < 4; r++) {
      float e0 = __builtin_amdgcn_exp2f(S0[r]);
      float e1 = __builtin_amdgcn_exp2f(S1[r]);
      lsum[r] += e0 + e1;
      Ps[sg*16 + quad*4 + r][mh*32 +      l15] = f2bf(e0);
      Ps[sg*16 + quad*4 + r][mh*32 + 16 + l15] = f2bf(e1);
    }
    __syncthreads();   // Ps(T) + Vs(T) visible to all

    short8 ap0 = *(const short8*)(&Ps[     l15][mh*32 + quad*8]);
    short8 ap1 = *(const short8*)(&Ps[16 + l15][mh*32 + quad*8]);
    short8 ap2 = *(const short8*)(&Ps[32 + l15][mh*32 + quad*8]);
    short8 ap3 = *(const short8*)(&Ps[48 + l15][mh*32 + quad*8]);
#pragma unroll
    for (int cg = 0; cg < 4; cg++) {
      short8 av = *(const short8*)(&Vs[sg*64 + cg*16 + l15][mh*32 + quad*8]);
      acc[cg][0] = __builtin_amdgcn_mfma_f32_16x16x32_bf16(av, ap0, acc[cg][0], 0,0,0);
      acc[cg][1] = __builtin_amdgcn_mfma_f32_16x16x32_bf16(av, ap1, acc[cg][1], 0,0,0);
      acc[cg][2] = __builtin_amdgcn_mfma_f32_16x16x32_bf16(av, ap2, acc[cg][2], 0,0,0);
      acc[cg][3] = __builtin_amdgcn_mfma_f32_16x16x32_bf16(av, ap3, acc[cg][3], 0,0,0);
    }
    __syncthreads();   // everyone done reading Vs/Ps of tile T

    if (T < 63) {
      *(short8*)(&Vs[vr][sh*32 +  0]) = nv0;
      *(short8*)(&Vs[vr][sh*32 +  8]) = nv1;
      *(short8*)(&Vs[vr][sh*32 + 16]) = nv2;
      *(short8*)(&Vs[vr][sh*32 + 24]) = nv3;
      kf0 = nk0; kf1 = nk1;
    }
  }

  // ---- L: reduce over l15, publish per m-half ----
#pragma unroll
  for (int r = 0; r < 4; r++) {
    float s = lsum[r];
    s += __shfl_xor(s, 1); s += __shfl_xor(s, 2);
    s += __shfl_xor(s, 4); s += __shfl_xor(s, 8);
    if (l15 == 0) Lbuf2[mh][sg*16 + quad*4 + r] = s;
  }

  // ---- combine mh halves of acc via LDS (2 rounds of 2 c-strips) ----
  float* poolf = reinterpret_cast<float*>(&Vs[0][0]);   // 32 KB of the 36 KB Vs
  __syncthreads();
#pragma unroll
  for (int g = 0; g < 2; g++) {
    if (mh == 1 && (sg >> 1) == g) {
#pragma unroll
      for (int cg = 0; cg < 4; cg++)
#pragma unroll
        for (int ng = 0; ng < 4; ng++)
#pragma unroll
          for (int r = 0; r < 4; r++)
            poolf[(sg & 1)*4096 + (cg*16 + quad*4 + r)*64 + ng*16 + l15] = acc[cg][ng][r];
    }
    __syncthreads();
    if (mh == 0 && (sg >> 1) == g) {
#pragma unroll
      for (int cg = 0; cg < 4; cg++)
#pragma unroll
        for (int ng = 0; ng < 4; ng++)
#pragma unroll
          for (int r = 0; r < 4; r++)
            acc[cg][ng][r] += poolf[(sg & 1)*4096 + (cg*16 + quad*4 + r)*64 + ng*16 + l15];
    }
    __syncthreads();
  }

  // ---- epilogue (mh==0 waves): out = gamma*O/l + x, coalesced rows ----
  if (mh == 0) {
    const float gm = gamma[0];
    float Lv[4];
#pragma unroll
    for (int ng = 0; ng < 4; ng++)
      Lv[ng] = 1.0f / (Lbuf2[0][ng*16 + l15] + Lbuf2[1][ng*16 + l15]);
#pragma unroll
    for (int cg = 0; cg < 4; cg++) {
#pragma unroll
      for (int ng = 0; ng < 4; ng++) {
#pragma unroll
        for (int r = 0; r < 4; r++) {
          size_t idx = ((size_t)b*CC + sg*64 + cg*16 + quad*4 + r)*NN + n0 + ng*16 + l15;
          out[idx] = gm * acc[cg][ng][r] * Lv[ng] + x[idx];
        }
      }
    }
  }
}

// ---------------------------------------------------------------------------
extern "C" void kernel_launch(void* const* d_in, const int* in_sizes, int n_in,
                              void* d_out, int out_size, void* d_ws, size_t ws_size,
                              hipStream_t stream) {
  const float* x     = (const float*)d_in[0];
  const float* Wq    = (const float*)d_in[1];
  const float* bq    = (const float*)d_in[2];
  const float* Wk    = (const float*)d_in[3];
  const float* bk    = (const float*)d_in[4];
  const float* Wv    = (const float*)d_in[5];
  const float* bv    = (const float*)d_in[6];
  const float* gamma = (const float*)d_in[7];
  float* out = (float*)d_out;

  char* ws = (char*)d_ws;
  // qb 1 MB | kb 1 MB | vb 8 MB | xT 8 MB | Wf 160 KB  = 18.16 MB
  if (ws_size < ((18u << 20) + (1u << 18))) return;   // loud-fail if ws short
  __hip_bfloat16* qb = (__hip_bfloat16*)(ws);                 // [B][N][32]
  __hip_bfloat16* kb = (__hip_bfloat16*)(ws + (1u << 20));    // [B][N][32]
  __hip_bfloat16* vb = (__hip_bfloat16*)(ws + (2u << 20));    // [B][C][N]
  __hip_bfloat16* xT = (__hip_bfloat16*)(ws + (10u << 20));   // [B][N][C]
  __hip_bfloat16* Wf = (__hip_bfloat16*)(ws + (18u << 20));   // frag-linear

  xpose_prep_kernel<<<dim3(1064), 256, 0, stream>>>(x, Wq, Wk, Wv, Wf, xT);
  qkv_kernel<<<dim3(128, 4), 256, 0, stream>>>(xT, Wf, bq, bk, bv, qb, kb, vb);
  attn_kernel<<<dim3(256), 512, 0, stream>>>(qb, kb, vb, x, gamma, out);
}